// Round 16
// baseline (287.020 us; speedup 1.0000x reference)
//
#include <hip/hip_runtime.h>
#include <math.h>

#define NN 100000
#define EE 1600000
#define HID 64
#define BKT 391                 // ceil(NN/256) buckets of 256 nodes
#define SLAB 5504               // slab capacity per bucket (mean ~4092)
#define CHUNK 4096              // edges per workgroup in placement pass
#define NWG ((EE + CHUNK - 1) / CHUNK)   // 391
#define TB (NN / 16)            // 6250 transform blocks (4 waves x 4 nodes)

typedef _Float16 f16;
typedef _Float16 f16x2 __attribute__((ext_vector_type(2)));

__device__ __forceinline__ f16x2 u2h(unsigned u) { return __builtin_bit_cast(f16x2, u); }
__device__ __forceinline__ unsigned h2u(f16x2 h) { return __builtin_bit_cast(unsigned, h); }

#if defined(__has_builtin) && __has_builtin(__builtin_amdgcn_fdot2)
__device__ __forceinline__ float dot2(f16x2 a, f16x2 b, float c) {
    return __builtin_amdgcn_fdot2(a, b, c, false);
}
#else
__device__ __forceinline__ float dot2(f16x2 a, f16x2 b, float c) {
    c = fmaf((float)a.x, (float)b.x, c);
    return fmaf((float)a.y, (float)b.y, c);
}
#endif

// ================= merged: CSR placement || layer-0 transform =================

__global__ void mt_kernel(const int* __restrict__ src, const int* __restrict__ dst,
                          int* __restrict__ bfill, unsigned* __restrict__ pairs,
                          const float* __restrict__ h,
                          const float* __restrict__ Wn, const float* __restrict__ bn,
                          const float* __restrict__ Wr,
                          f16* __restrict__ hn, f16* __restrict__ hrb,
                          const float* __restrict__ Wn1, const float* __restrict__ Wr1,
                          const float* __restrict__ Wn2, const float* __restrict__ Wr2,
                          const float* __restrict__ Wp1, unsigned* __restrict__ w16) {
    __shared__ int lc[BKT];
    __shared__ int lbase[BKT];
    int t = threadIdx.x;

    if (blockIdx.x < NWG) {
        for (int b = t; b < BKT; b += 256) lc[b] = 0;
        __syncthreads();
        int base = blockIdx.x * CHUNK;
        int myd[CHUNK / 256];
#pragma unroll
        for (int j = 0; j < CHUNK / 256; ++j) {
            int i = base + j * 256 + t;
            myd[j] = (i < EE) ? dst[i] : -1;
            if (myd[j] >= 0) atomicAdd(&lc[myd[j] >> 8], 1);
        }
        __syncthreads();
        for (int b = t; b < BKT; b += 256) {
            int c = lc[b];
            if (c) {
                int ofs = atomicAdd(&bfill[b], c);
                if (ofs + c > SLAB) ofs = SLAB - c;   // statistically unreachable
                lbase[b] = b * SLAB + ofs;
            }
        }
        __syncthreads();
        for (int b = t; b < BKT; b += 256) lc[b] = 0;
        __syncthreads();
#pragma unroll
        for (int j = 0; j < CHUNK / 256; ++j) {
            int i = base + j * 256 + t;
            if (myd[j] >= 0) {
                int b = myd[j] >> 8;
                int r = atomicAdd(&lc[b], 1);
                pairs[lbase[b] + r] = (unsigned)src[i] | ((unsigned)(myd[j] & 255) << 24);
            }
        }
        return;
    }

    int bb = blockIdx.x - NWG;

    if (bb < 40) {  // f16 weight pack
        int id = bb * 256 + t;
        int mat = id >> 11;
        int p = (id >> 6) & 31;
        int j = id & 63;
        const float* W = (mat == 0) ? Wn1 : (mat == 1) ? Wr1 :
                         (mat == 2) ? Wn2 : (mat == 3) ? Wr2 : Wp1;
        f16x2 v;
        v.x = (f16)W[(2 * p) * HID + j];
        v.y = (f16)W[(2 * p + 1) * HID + j];
        w16[id] = h2u(v);
    }

    int lane = t & 63;
    int wid = (bb * 256 + t) >> 6;
    int m0 = __builtin_amdgcn_readfirstlane(wid << 2);
    const float* h0 = h + (size_t)m0 * 32;

    float an0 = 0.f, an1 = 0.f, an2 = 0.f, an3 = 0.f;
    float ar0 = 0.f, ar1 = 0.f, ar2 = 0.f, ar3 = 0.f;
#pragma unroll
    for (int k = 0; k < 32; ++k) {
        float wn = Wn[k * HID + lane];
        float wr = Wr[k * HID + lane];
        float hk0 = h0[k], hk1 = h0[32 + k], hk2 = h0[64 + k], hk3 = h0[96 + k];
        an0 = fmaf(hk0, wn, an0); ar0 = fmaf(hk0, wr, ar0);
        an1 = fmaf(hk1, wn, an1); ar1 = fmaf(hk1, wr, ar1);
        an2 = fmaf(hk2, wn, an2); ar2 = fmaf(hk2, wr, ar2);
        an3 = fmaf(hk3, wn, an3); ar3 = fmaf(hk3, wr, ar3);
    }
    float b = bn[lane];
    size_t o = (size_t)m0 * HID + lane;
    hn[o] = (f16)an0; hn[o + HID] = (f16)an1;
    hn[o + 2 * HID] = (f16)an2; hn[o + 3 * HID] = (f16)an3;
    hrb[o] = (f16)(ar0 + b); hrb[o + HID] = (f16)(ar1 + b);
    hrb[o + 2 * HID] = (f16)(ar2 + b); hrb[o + 3 * HID] = (f16)(ar3 + b);
}

// ================= per-bucket counting sort + degree-sorted perm ==============
// Additionally counting-sorts the bucket's 256 nodes by degree (descending)
// into perm[b*256 ..]: gt/gh waves then pack 4 degree-adjacent nodes -> equal
// loop trips, no divergence waste. Pure reordering: per-node math identical.

__global__ void build_kernel(const unsigned* __restrict__ pairs,
                             const int* __restrict__ bfill,
                             int* __restrict__ rs, int* __restrict__ re,
                             float* __restrict__ inv, int* __restrict__ col,
                             int* __restrict__ perm) {
    __shared__ unsigned s_pk[SLAB];
    __shared__ int ncnt[256];
    __shared__ int nexcl[256];
    __shared__ int dh[64];
    __shared__ int dh2[64];
    int b = blockIdx.x;
    int t = threadIdx.x;
    int s0 = b * SLAB;
    int ce = bfill[b]; if (ce > SLAB) ce = SLAB;
    ncnt[t] = 0;
    for (int e = t; e < ce; e += 256) s_pk[e] = pairs[s0 + e];
    __syncthreads();
    for (int e = t; e < ce; e += 256) atomicAdd(&ncnt[s_pk[e] >> 24], 1);
    __syncthreads();
    int c = ncnt[t];
    nexcl[t] = c;
    __syncthreads();
    for (int off = 1; off < 256; off <<= 1) {
        int u = (t >= off) ? nexcl[t - off] : 0;
        __syncthreads();
        nexcl[t] += u;
        __syncthreads();
    }
    int excl = nexcl[t] - c;
    int node = (b << 8) + t;
    if (node < NN) {
        rs[node] = s0 + excl;
        re[node] = s0 + excl + c;
        inv[node] = (c > 0) ? (1.0f / (float)c) : 0.0f;
    }
    __syncthreads();

    // ---- degree counting sort (descending) -> perm ----
    if (t < 64) dh[t] = 0;
    __syncthreads();
    int key = 63 - ((c < 63) ? c : 63);       // bin 0 = highest degree
    int rank = 0;
    if (node < NN) rank = atomicAdd(&dh[key], 1);
    __syncthreads();
    if (t < 64) dh2[t] = dh[t];
    __syncthreads();
    for (int off = 1; off < 64; off <<= 1) {
        int u = (t >= off && t < 64) ? dh[t - off] : 0;
        __syncthreads();
        if (t < 64) dh[t] += u;
        __syncthreads();
    }
    if (node < NN) {
        int pos = dh[key] - dh2[key] + rank;  // exclusive base + rank
        perm[(b << 8) + pos] = node;
    }
    __syncthreads();

    // ---- scatter col ----
    nexcl[t] = excl;
    ncnt[t] = 0;
    __syncthreads();
    for (int e = t; e < ce; e += 256) {
        unsigned pk = s_pk[e];
        int d = pk >> 24;
        int r = atomicAdd(&ncnt[d], 1);
        col[s0 + nexcl[d] + r] = (int)(pk & 0xFFFFFFu);
    }
}

// ================= quarter-wave gather (device helper) =================
// 8-deep main loop (best measured) + packed-f16 accumulation.

__device__ __forceinline__ void qgather(const uint2* __restrict__ rp,
                                        const int* __restrict__ col,
                                        int e, int en, int fl,
                                        f16x2& s0, f16x2& s1) {
    while (e + 8 <= en) {
        int c0 = col[e],     c1 = col[e + 1], c2 = col[e + 2], c3 = col[e + 3];
        int c4 = col[e + 4], c5 = col[e + 5], c6 = col[e + 6], c7 = col[e + 7];
        uint2 v0 = rp[(size_t)c0 * 16 + fl];
        uint2 v1 = rp[(size_t)c1 * 16 + fl];
        uint2 v2 = rp[(size_t)c2 * 16 + fl];
        uint2 v3 = rp[(size_t)c3 * 16 + fl];
        uint2 v4 = rp[(size_t)c4 * 16 + fl];
        uint2 v5 = rp[(size_t)c5 * 16 + fl];
        uint2 v6 = rp[(size_t)c6 * 16 + fl];
        uint2 v7 = rp[(size_t)c7 * 16 + fl];
        s0 += u2h(v0.x); s1 += u2h(v0.y);
        s0 += u2h(v1.x); s1 += u2h(v1.y);
        s0 += u2h(v2.x); s1 += u2h(v2.y);
        s0 += u2h(v3.x); s1 += u2h(v3.y);
        s0 += u2h(v4.x); s1 += u2h(v4.y);
        s0 += u2h(v5.x); s1 += u2h(v5.y);
        s0 += u2h(v6.x); s1 += u2h(v6.y);
        s0 += u2h(v7.x); s1 += u2h(v7.y);
        e += 8;
    }
    if (e + 4 <= en) {
        int c0 = col[e], c1 = col[e + 1], c2 = col[e + 2], c3 = col[e + 3];
        uint2 v0 = rp[(size_t)c0 * 16 + fl];
        uint2 v1 = rp[(size_t)c1 * 16 + fl];
        uint2 v2 = rp[(size_t)c2 * 16 + fl];
        uint2 v3 = rp[(size_t)c3 * 16 + fl];
        s0 += u2h(v0.x); s1 += u2h(v0.y);
        s0 += u2h(v1.x); s1 += u2h(v1.y);
        s0 += u2h(v2.x); s1 += u2h(v2.y);
        s0 += u2h(v3.x); s1 += u2h(v3.y);
        e += 4;
    }
    while (e < en) {
        uint2 v = rp[(size_t)col[e] * 16 + fl];
        s0 += u2h(v.x); s1 += u2h(v.y);
        ++e;
    }
}

// ================= fused gather_k + transform_{k+1} (perm-packed) =============

__global__ void gt_kernel(const f16* __restrict__ An,
                          const int* __restrict__ rs, const int* __restrict__ re,
                          const int* __restrict__ col, const float* __restrict__ inv,
                          const int* __restrict__ perm,
                          f16* C,
                          const unsigned* __restrict__ Wn16, const float* __restrict__ bn,
                          const unsigned* __restrict__ Wr16,
                          f16* __restrict__ Aout) {
    int lane = threadIdx.x & 63;
    int wid = __builtin_amdgcn_readfirstlane((int)((blockIdx.x * blockDim.x + threadIdx.x) >> 6));
    int base = wid << 2;
    int q = lane >> 4;
    int fl = lane & 15;
    int m = perm[base + q];               // per-quarter node (degree-adjacent)

    f16x2 s0 = (f16x2)0, s1 = (f16x2)0;
    qgather((const uint2*)An, col, rs[m], re[m], fl, s0, s1);

    float iv = inv[m];
    uint2 cur = ((const uint2*)C)[(size_t)m * 16 + fl];
    f16x2 q0 = u2h(cur.x), q1 = u2h(cur.y);
    f16x2 hA, hB;
    hA.x = (f16)fmaxf(fmaf((float)s0.x, iv, (float)q0.x), 0.f);
    hA.y = (f16)fmaxf(fmaf((float)s0.y, iv, (float)q0.y), 0.f);
    hB.x = (f16)fmaxf(fmaf((float)s1.x, iv, (float)q1.x), 0.f);
    hB.y = (f16)fmaxf(fmaf((float)s1.y, iv, (float)q1.y), 0.f);
    unsigned hx = h2u(hA), hy = h2u(hB);

    float an[4] = {0.f, 0.f, 0.f, 0.f};
    float ar[4] = {0.f, 0.f, 0.f, 0.f};
#pragma unroll
    for (int kk = 0; kk < 16; ++kk) {
        f16x2 wnA = u2h(Wn16[(2 * kk) * HID + lane]);
        f16x2 wnB = u2h(Wn16[(2 * kk + 1) * HID + lane]);
        f16x2 wrA = u2h(Wr16[(2 * kk) * HID + lane]);
        f16x2 wrB = u2h(Wr16[(2 * kk + 1) * HID + lane]);
#pragma unroll
        for (int n = 0; n < 4; ++n) {
            f16x2 px = u2h(__shfl(hx, (n << 4) + kk));
            f16x2 py = u2h(__shfl(hy, (n << 4) + kk));
            an[n] = dot2(px, wnA, an[n]);
            an[n] = dot2(py, wnB, an[n]);
            ar[n] = dot2(px, wrA, ar[n]);
            ar[n] = dot2(py, wrB, ar[n]);
        }
    }
    float b = bn[lane];
#pragma unroll
    for (int n = 0; n < 4; ++n) {
        int mn = perm[base + n];          // wave-uniform scalar load
        size_t o = (size_t)mn * HID + lane;
        Aout[o] = (f16)an[n];
        C[o] = (f16)(ar[n] + b);
    }
}

// ================= fused gather_2 (no relu) + predictor head ==================

__global__ void gh_kernel(const f16* __restrict__ An,
                          const int* __restrict__ rs, const int* __restrict__ re,
                          const int* __restrict__ col, const float* __restrict__ inv,
                          const int* __restrict__ perm,
                          const f16* __restrict__ C,
                          const unsigned* __restrict__ Wp116, const float* __restrict__ bp1,
                          const float* __restrict__ Wp2, const float* __restrict__ bp2,
                          float* __restrict__ out) {
    int lane = threadIdx.x & 63;
    int wid = __builtin_amdgcn_readfirstlane((int)((blockIdx.x * blockDim.x + threadIdx.x) >> 6));
    int base = wid << 2;
    int q = lane >> 4;
    int fl = lane & 15;
    int m = perm[base + q];

    f16x2 s0 = (f16x2)0, s1 = (f16x2)0;
    qgather((const uint2*)An, col, rs[m], re[m], fl, s0, s1);

    float iv = inv[m];
    uint2 cur = ((const uint2*)C)[(size_t)m * 16 + fl];
    f16x2 q0 = u2h(cur.x), q1 = u2h(cur.y);
    f16x2 hA, hB;
    hA.x = (f16)fmaf((float)s0.x, iv, (float)q0.x);
    hA.y = (f16)fmaf((float)s0.y, iv, (float)q0.y);
    hB.x = (f16)fmaf((float)s1.x, iv, (float)q1.x);
    hB.y = (f16)fmaf((float)s1.y, iv, (float)q1.y);
    unsigned hx = h2u(hA), hy = h2u(hB);

    float tn[4] = {0.f, 0.f, 0.f, 0.f};
#pragma unroll
    for (int kk = 0; kk < 16; ++kk) {
        f16x2 wA = u2h(Wp116[(2 * kk) * HID + lane]);
        f16x2 wB = u2h(Wp116[(2 * kk + 1) * HID + lane]);
#pragma unroll
        for (int n = 0; n < 4; ++n) {
            f16x2 px = u2h(__shfl(hx, (n << 4) + kk));
            f16x2 py = u2h(__shfl(hy, (n << 4) + kk));
            tn[n] = dot2(px, wA, tn[n]);
            tn[n] = dot2(py, wB, tn[n]);
        }
    }
    float b = bp1[lane], w2v = Wp2[lane];
    float r0 = fmaxf(tn[0] + b, 0.f) * w2v;
    float r1 = fmaxf(tn[1] + b, 0.f) * w2v;
    float r2 = fmaxf(tn[2] + b, 0.f) * w2v;
    float r3 = fmaxf(tn[3] + b, 0.f) * w2v;
#pragma unroll
    for (int off = 32; off > 0; off >>= 1) {
        r0 += __shfl_xor(r0, off);
        r1 += __shfl_xor(r1, off);
        r2 += __shfl_xor(r2, off);
        r3 += __shfl_xor(r3, off);
    }
    if (lane == 0) {
        float bb = bp2[0];
        out[perm[base]]     = 1.f / (1.f + expf(-(r0 + bb)));
        out[perm[base + 1]] = 1.f / (1.f + expf(-(r1 + bb)));
        out[perm[base + 2]] = 1.f / (1.f + expf(-(r2 + bb)));
        out[perm[base + 3]] = 1.f / (1.f + expf(-(r3 + bb)));
    }
}

extern "C" void kernel_launch(void* const* d_in, const int* in_sizes, int n_in,
                              void* d_out, int out_size, void* d_ws, size_t ws_size,
                              hipStream_t stream) {
    const float* x   = (const float*)d_in[0];
    const int* eidx  = (const int*)d_in[1];
    const float* Wn0 = (const float*)d_in[2];
    const float* bn0 = (const float*)d_in[3];
    const float* Wr0 = (const float*)d_in[4];
    const float* Wn1 = (const float*)d_in[5];
    const float* bn1 = (const float*)d_in[6];
    const float* Wr1 = (const float*)d_in[7];
    const float* Wn2 = (const float*)d_in[8];
    const float* bn2 = (const float*)d_in[9];
    const float* Wr2 = (const float*)d_in[10];
    const float* Wp1 = (const float*)d_in[11];
    const float* bp1 = (const float*)d_in[12];
    const float* Wp2 = (const float*)d_in[13];
    const float* bp2 = (const float*)d_in[14];
    float* out = (float*)d_out;

    const int* src = eidx;
    const int* dst = eidx + EE;

    char* w = (char*)d_ws;
    size_t off = 0;
    auto carve = [&](size_t bytes) -> void* {
        void* p = w + off;
        off = (off + bytes + 255) & ~(size_t)255;
        return p;
    };
    int*   rsA    = (int*)carve((size_t)NN * 4);
    int*   reA    = (int*)carve((size_t)NN * 4);
    float* inv    = (float*)carve((size_t)NN * 4);
    int*   perm   = (int*)carve((size_t)NN * 4);
    int*   col    = (int*)carve((size_t)BKT * SLAB * 4);
    int*   bfill  = (int*)carve((size_t)BKT * 4);
    unsigned* w16 = (unsigned*)carve((size_t)5 * 2048 * 4);
    f16*   A0     = (f16*)carve((size_t)NN * HID * 2);
    f16*   A1     = (f16*)carve((size_t)NN * HID * 2);
    f16*   C      = (f16*)carve((size_t)NN * HID * 2);
    unsigned* pairs = (unsigned*)carve((size_t)BKT * SLAB * 4);
    (void)ws_size;

    unsigned* Wn1_16 = w16;
    unsigned* Wr1_16 = w16 + 2048;
    unsigned* Wn2_16 = w16 + 4096;
    unsigned* Wr2_16 = w16 + 6144;
    unsigned* Wp1_16 = w16 + 8192;

    hipMemsetAsync(bfill, 0, (size_t)BKT * 4, stream);

    // merged: CSR placement || layer-0 transform (+ weight pack)
    mt_kernel<<<NWG + TB, 256, 0, stream>>>(src, dst, bfill, pairs,
                                            x, Wn0, bn0, Wr0, A0, C,
                                            Wn1, Wr1, Wn2, Wr2, Wp1, w16);
    // per-bucket counting sort + degree-sorted perm
    build_kernel<<<BKT, 256, 0, stream>>>(pairs, bfill, rsA, reA, inv, col, perm);

    // gather0 + transform1
    gt_kernel<<<TB, 256, 0, stream>>>(A0, rsA, reA, col, inv, perm, C, Wn1_16, bn1, Wr1_16, A1);
    // gather1 + transform2
    gt_kernel<<<TB, 256, 0, stream>>>(A1, rsA, reA, col, inv, perm, C, Wn2_16, bn2, Wr2_16, A0);
    // gather2 + head
    gh_kernel<<<TB, 256, 0, stream>>>(A0, rsA, reA, col, inv, perm, C, Wp1_16, bp1, Wp2, bp2, out);
}

// Round 17
// 275.609 us; speedup vs baseline: 1.0414x; 1.0414x over previous
//
#include <hip/hip_runtime.h>
#include <math.h>

#define NN 100000
#define EE 1600000
#define HID 64
#define BKT 391                 // ceil(NN/256) buckets of 256 nodes
#define SLAB 5504               // slab capacity per bucket (mean ~4092)
#define CHUNK 4096              // edges per workgroup in placement pass
#define NWG ((EE + CHUNK - 1) / CHUNK)   // 391
#define TB (NN / 16)            // 6250 transform blocks (4 waves x 4 nodes)

typedef _Float16 f16;
typedef _Float16 f16x2 __attribute__((ext_vector_type(2)));

__device__ __forceinline__ f16x2 u2h(unsigned u) { return __builtin_bit_cast(f16x2, u); }
__device__ __forceinline__ unsigned h2u(f16x2 h) { return __builtin_bit_cast(unsigned, h); }

#if defined(__has_builtin) && __has_builtin(__builtin_amdgcn_fdot2)
__device__ __forceinline__ float dot2(f16x2 a, f16x2 b, float c) {
    return __builtin_amdgcn_fdot2(a, b, c, false);
}
#else
__device__ __forceinline__ float dot2(f16x2 a, f16x2 b, float c) {
    c = fmaf((float)a.x, (float)b.x, c);
    return fmaf((float)a.y, (float)b.y, c);
}
#endif

// ================= merged: CSR placement (blocks 0..NWG-1) ====================
// ================= || layer-0 transform + weight pack (blocks NWG..) ==========

__global__ void mt_kernel(const int* __restrict__ src, const int* __restrict__ dst,
                          int* __restrict__ bfill, unsigned* __restrict__ pairs,
                          const float* __restrict__ h,
                          const float* __restrict__ Wn, const float* __restrict__ bn,
                          const float* __restrict__ Wr,
                          f16* __restrict__ hn, f16* __restrict__ hrb,
                          const float* __restrict__ Wn1, const float* __restrict__ Wr1,
                          const float* __restrict__ Wn2, const float* __restrict__ Wr2,
                          const float* __restrict__ Wp1, unsigned* __restrict__ w16) {
    __shared__ int lc[BKT];
    __shared__ int lbase[BKT];
    int t = threadIdx.x;

    if (blockIdx.x < NWG) {
        // ---- CSR placement ----
        for (int b = t; b < BKT; b += 256) lc[b] = 0;
        __syncthreads();
        int base = blockIdx.x * CHUNK;
        int myd[CHUNK / 256];
#pragma unroll
        for (int j = 0; j < CHUNK / 256; ++j) {
            int i = base + j * 256 + t;
            myd[j] = (i < EE) ? dst[i] : -1;
            if (myd[j] >= 0) atomicAdd(&lc[myd[j] >> 8], 1);
        }
        __syncthreads();
        for (int b = t; b < BKT; b += 256) {
            int c = lc[b];
            if (c) {
                int ofs = atomicAdd(&bfill[b], c);
                if (ofs + c > SLAB) ofs = SLAB - c;   // statistically unreachable
                lbase[b] = b * SLAB + ofs;
            }
        }
        __syncthreads();
        for (int b = t; b < BKT; b += 256) lc[b] = 0;
        __syncthreads();
#pragma unroll
        for (int j = 0; j < CHUNK / 256; ++j) {
            int i = base + j * 256 + t;
            if (myd[j] >= 0) {
                int b = myd[j] >> 8;
                int r = atomicAdd(&lc[b], 1);
                pairs[lbase[b] + r] = (unsigned)src[i] | ((unsigned)(myd[j] & 255) << 24);
            }
        }
        return;
    }

    int bb = blockIdx.x - NWG;

    // ---- f16 weight pack (first 40 transform blocks) ----
    if (bb < 40) {
        int id = bb * 256 + t;
        int mat = id >> 11;            // 0..4
        int p = (id >> 6) & 31;        // pair index
        int j = id & 63;               // output column
        const float* W = (mat == 0) ? Wn1 : (mat == 1) ? Wr1 :
                         (mat == 2) ? Wn2 : (mat == 3) ? Wr2 : Wp1;
        f16x2 v;
        v.x = (f16)W[(2 * p) * HID + j];
        v.y = (f16)W[(2 * p + 1) * HID + j];
        w16[id] = h2u(v);
    }

    // ---- layer-0 transform: 4 nodes/wave, lane = output column ----
    int lane = t & 63;
    int wid = (bb * 256 + t) >> 6;
    int m0 = __builtin_amdgcn_readfirstlane(wid << 2);
    const float* h0 = h + (size_t)m0 * 32;

    float an0 = 0.f, an1 = 0.f, an2 = 0.f, an3 = 0.f;
    float ar0 = 0.f, ar1 = 0.f, ar2 = 0.f, ar3 = 0.f;
#pragma unroll
    for (int k = 0; k < 32; ++k) {
        float wn = Wn[k * HID + lane];
        float wr = Wr[k * HID + lane];
        float hk0 = h0[k], hk1 = h0[32 + k], hk2 = h0[64 + k], hk3 = h0[96 + k];
        an0 = fmaf(hk0, wn, an0); ar0 = fmaf(hk0, wr, ar0);
        an1 = fmaf(hk1, wn, an1); ar1 = fmaf(hk1, wr, ar1);
        an2 = fmaf(hk2, wn, an2); ar2 = fmaf(hk2, wr, ar2);
        an3 = fmaf(hk3, wn, an3); ar3 = fmaf(hk3, wr, ar3);
    }
    float b = bn[lane];
    size_t o = (size_t)m0 * HID + lane;
    hn[o] = (f16)an0; hn[o + HID] = (f16)an1;
    hn[o + 2 * HID] = (f16)an2; hn[o + 3 * HID] = (f16)an3;
    hrb[o] = (f16)(ar0 + b); hrb[o + HID] = (f16)(ar1 + b);
    hrb[o + 2 * HID] = (f16)(ar2 + b); hrb[o + 3 * HID] = (f16)(ar3 + b);
}

// ================= per-bucket counting sort =================

__global__ void build_kernel(const unsigned* __restrict__ pairs,
                             const int* __restrict__ bfill,
                             int* __restrict__ rs, int* __restrict__ re,
                             float* __restrict__ inv, int* __restrict__ col) {
    __shared__ unsigned s_pk[SLAB];
    __shared__ int ncnt[256];
    __shared__ int nexcl[256];
    int b = blockIdx.x;
    int t = threadIdx.x;
    int s0 = b * SLAB;
    int ce = bfill[b]; if (ce > SLAB) ce = SLAB;
    ncnt[t] = 0;
    for (int e = t; e < ce; e += 256) s_pk[e] = pairs[s0 + e];
    __syncthreads();
    for (int e = t; e < ce; e += 256) atomicAdd(&ncnt[s_pk[e] >> 24], 1);
    __syncthreads();
    int c = ncnt[t];
    nexcl[t] = c;
    __syncthreads();
    for (int off = 1; off < 256; off <<= 1) {
        int u = (t >= off) ? nexcl[t - off] : 0;
        __syncthreads();
        nexcl[t] += u;
        __syncthreads();
    }
    int excl = nexcl[t] - c;
    int node = (b << 8) + t;
    if (node < NN) {
        rs[node] = s0 + excl;
        re[node] = s0 + excl + c;
        inv[node] = (c > 0) ? (1.0f / (float)c) : 0.0f;
    }
    __syncthreads();
    nexcl[t] = excl;
    ncnt[t] = 0;
    __syncthreads();
    for (int e = t; e < ce; e += 256) {
        unsigned pk = s_pk[e];
        int d = pk >> 24;
        int r = atomicAdd(&ncnt[d], 1);
        col[s0 + nexcl[d] + r] = (int)(pk & 0xFFFFFFu);
    }
}

// ================= quarter-wave gather (device helper) =================
// Wave = 4 nodes: lane = (node quarter)<<4 | fl. Each lane loads uint2 (4 f16)
// of a neighbor row; 8-deep main loop (best measured, r12) -> 8 loads (4KB,
// 32 rows) in flight. Packed-f16 accumulation (v_pk_add_f16, accuracy verified
// r13: absmax unchanged).

__device__ __forceinline__ void qgather(const uint2* __restrict__ rp,
                                        const int* __restrict__ col,
                                        int e, int en, int fl,
                                        f16x2& s0, f16x2& s1) {
    while (e + 8 <= en) {
        int c0 = col[e],     c1 = col[e + 1], c2 = col[e + 2], c3 = col[e + 3];
        int c4 = col[e + 4], c5 = col[e + 5], c6 = col[e + 6], c7 = col[e + 7];
        uint2 v0 = rp[(size_t)c0 * 16 + fl];
        uint2 v1 = rp[(size_t)c1 * 16 + fl];
        uint2 v2 = rp[(size_t)c2 * 16 + fl];
        uint2 v3 = rp[(size_t)c3 * 16 + fl];
        uint2 v4 = rp[(size_t)c4 * 16 + fl];
        uint2 v5 = rp[(size_t)c5 * 16 + fl];
        uint2 v6 = rp[(size_t)c6 * 16 + fl];
        uint2 v7 = rp[(size_t)c7 * 16 + fl];
        s0 += u2h(v0.x); s1 += u2h(v0.y);
        s0 += u2h(v1.x); s1 += u2h(v1.y);
        s0 += u2h(v2.x); s1 += u2h(v2.y);
        s0 += u2h(v3.x); s1 += u2h(v3.y);
        s0 += u2h(v4.x); s1 += u2h(v4.y);
        s0 += u2h(v5.x); s1 += u2h(v5.y);
        s0 += u2h(v6.x); s1 += u2h(v6.y);
        s0 += u2h(v7.x); s1 += u2h(v7.y);
        e += 8;
    }
    if (e + 4 <= en) {
        int c0 = col[e], c1 = col[e + 1], c2 = col[e + 2], c3 = col[e + 3];
        uint2 v0 = rp[(size_t)c0 * 16 + fl];
        uint2 v1 = rp[(size_t)c1 * 16 + fl];
        uint2 v2 = rp[(size_t)c2 * 16 + fl];
        uint2 v3 = rp[(size_t)c3 * 16 + fl];
        s0 += u2h(v0.x); s1 += u2h(v0.y);
        s0 += u2h(v1.x); s1 += u2h(v1.y);
        s0 += u2h(v2.x); s1 += u2h(v2.y);
        s0 += u2h(v3.x); s1 += u2h(v3.y);
        e += 4;
    }
    while (e < en) {
        uint2 v = rp[(size_t)col[e] * 16 + fl];
        s0 += u2h(v.x); s1 += u2h(v.y);
        ++e;
    }
}

// ================= fused gather_k + transform_{k+1} (dot2 path) ===============

__global__ void gt_kernel(const f16* __restrict__ An,
                          const int* __restrict__ rs, const int* __restrict__ re,
                          const int* __restrict__ col, const float* __restrict__ inv,
                          f16* C,
                          const unsigned* __restrict__ Wn16, const float* __restrict__ bn,
                          const unsigned* __restrict__ Wr16,
                          f16* __restrict__ Aout) {
    int lane = threadIdx.x & 63;
    int wid = (blockIdx.x * blockDim.x + threadIdx.x) >> 6;
    int m0 = wid << 2;
    int m = m0 + (lane >> 4);
    int fl = lane & 15;

    f16x2 s0 = (f16x2)0, s1 = (f16x2)0;
    qgather((const uint2*)An, col, rs[m], re[m], fl, s0, s1);

    // h_{k+1}[m] = relu(inv*agg + hrb_k[m]); lane fl holds feats 4fl..4fl+3
    float iv = inv[m];
    uint2 cur = ((const uint2*)C)[(size_t)m * 16 + fl];
    f16x2 q0 = u2h(cur.x), q1 = u2h(cur.y);
    f16x2 hA, hB;
    hA.x = (f16)fmaxf(fmaf((float)s0.x, iv, (float)q0.x), 0.f);
    hA.y = (f16)fmaxf(fmaf((float)s0.y, iv, (float)q0.y), 0.f);
    hB.x = (f16)fmaxf(fmaf((float)s1.x, iv, (float)q1.x), 0.f);
    hB.y = (f16)fmaxf(fmaf((float)s1.y, iv, (float)q1.y), 0.f);
    unsigned hx = h2u(hA), hy = h2u(hB);

    float an[4] = {0.f, 0.f, 0.f, 0.f};
    float ar[4] = {0.f, 0.f, 0.f, 0.f};
#pragma unroll
    for (int kk = 0; kk < 16; ++kk) {
        f16x2 wnA = u2h(Wn16[(2 * kk) * HID + lane]);
        f16x2 wnB = u2h(Wn16[(2 * kk + 1) * HID + lane]);
        f16x2 wrA = u2h(Wr16[(2 * kk) * HID + lane]);
        f16x2 wrB = u2h(Wr16[(2 * kk + 1) * HID + lane]);
#pragma unroll
        for (int n = 0; n < 4; ++n) {
            f16x2 px = u2h(__shfl(hx, (n << 4) + kk));
            f16x2 py = u2h(__shfl(hy, (n << 4) + kk));
            an[n] = dot2(px, wnA, an[n]);
            an[n] = dot2(py, wnB, an[n]);
            ar[n] = dot2(px, wrA, ar[n]);
            ar[n] = dot2(py, wrB, ar[n]);
        }
    }
    float b = bn[lane];
    size_t o = (size_t)m0 * HID + lane;
#pragma unroll
    for (int n = 0; n < 4; ++n) {
        Aout[o + n * HID] = (f16)an[n];
        C[o + n * HID] = (f16)(ar[n] + b);
    }
}

// ================= fused gather_2 (no relu) + predictor head (dot2) ===========

__global__ void gh_kernel(const f16* __restrict__ An,
                          const int* __restrict__ rs, const int* __restrict__ re,
                          const int* __restrict__ col, const float* __restrict__ inv,
                          const f16* __restrict__ C,
                          const unsigned* __restrict__ Wp116, const float* __restrict__ bp1,
                          const float* __restrict__ Wp2, const float* __restrict__ bp2,
                          float* __restrict__ out) {
    int lane = threadIdx.x & 63;
    int wid = (blockIdx.x * blockDim.x + threadIdx.x) >> 6;
    int m0 = wid << 2;
    int m = m0 + (lane >> 4);
    int fl = lane & 15;

    f16x2 s0 = (f16x2)0, s1 = (f16x2)0;
    qgather((const uint2*)An, col, rs[m], re[m], fl, s0, s1);

    float iv = inv[m];
    uint2 cur = ((const uint2*)C)[(size_t)m * 16 + fl];
    f16x2 q0 = u2h(cur.x), q1 = u2h(cur.y);
    f16x2 hA, hB;
    hA.x = (f16)fmaf((float)s0.x, iv, (float)q0.x);
    hA.y = (f16)fmaf((float)s0.y, iv, (float)q0.y);
    hB.x = (f16)fmaf((float)s1.x, iv, (float)q1.x);
    hB.y = (f16)fmaf((float)s1.y, iv, (float)q1.y);
    unsigned hx = h2u(hA), hy = h2u(hB);

    float tn[4] = {0.f, 0.f, 0.f, 0.f};
#pragma unroll
    for (int kk = 0; kk < 16; ++kk) {
        f16x2 wA = u2h(Wp116[(2 * kk) * HID + lane]);
        f16x2 wB = u2h(Wp116[(2 * kk + 1) * HID + lane]);
#pragma unroll
        for (int n = 0; n < 4; ++n) {
            f16x2 px = u2h(__shfl(hx, (n << 4) + kk));
            f16x2 py = u2h(__shfl(hy, (n << 4) + kk));
            tn[n] = dot2(px, wA, tn[n]);
            tn[n] = dot2(py, wB, tn[n]);
        }
    }
    float b = bp1[lane], w2v = Wp2[lane];
    float r0 = fmaxf(tn[0] + b, 0.f) * w2v;
    float r1 = fmaxf(tn[1] + b, 0.f) * w2v;
    float r2 = fmaxf(tn[2] + b, 0.f) * w2v;
    float r3 = fmaxf(tn[3] + b, 0.f) * w2v;
#pragma unroll
    for (int off = 32; off > 0; off >>= 1) {
        r0 += __shfl_xor(r0, off);
        r1 += __shfl_xor(r1, off);
        r2 += __shfl_xor(r2, off);
        r3 += __shfl_xor(r3, off);
    }
    if (lane == 0) {
        float bb = bp2[0];
        out[m0]     = 1.f / (1.f + expf(-(r0 + bb)));
        out[m0 + 1] = 1.f / (1.f + expf(-(r1 + bb)));
        out[m0 + 2] = 1.f / (1.f + expf(-(r2 + bb)));
        out[m0 + 3] = 1.f / (1.f + expf(-(r3 + bb)));
    }
}

extern "C" void kernel_launch(void* const* d_in, const int* in_sizes, int n_in,
                              void* d_out, int out_size, void* d_ws, size_t ws_size,
                              hipStream_t stream) {
    const float* x   = (const float*)d_in[0];
    const int* eidx  = (const int*)d_in[1];
    const float* Wn0 = (const float*)d_in[2];
    const float* bn0 = (const float*)d_in[3];
    const float* Wr0 = (const float*)d_in[4];
    const float* Wn1 = (const float*)d_in[5];
    const float* bn1 = (const float*)d_in[6];
    const float* Wr1 = (const float*)d_in[7];
    const float* Wn2 = (const float*)d_in[8];
    const float* bn2 = (const float*)d_in[9];
    const float* Wr2 = (const float*)d_in[10];
    const float* Wp1 = (const float*)d_in[11];
    const float* bp1 = (const float*)d_in[12];
    const float* Wp2 = (const float*)d_in[13];
    const float* bp2 = (const float*)d_in[14];
    float* out = (float*)d_out;

    const int* src = eidx;
    const int* dst = eidx + EE;

    char* w = (char*)d_ws;
    size_t off = 0;
    auto carve = [&](size_t bytes) -> void* {
        void* p = w + off;
        off = (off + bytes + 255) & ~(size_t)255;
        return p;
    };
    int*   rsA    = (int*)carve((size_t)NN * 4);
    int*   reA    = (int*)carve((size_t)NN * 4);
    float* inv    = (float*)carve((size_t)NN * 4);
    int*   col    = (int*)carve((size_t)BKT * SLAB * 4);   // slab layout
    int*   bfill  = (int*)carve((size_t)BKT * 4);
    unsigned* w16 = (unsigned*)carve((size_t)5 * 2048 * 4); // packed f16 weights
    f16*   A0     = (f16*)carve((size_t)NN * HID * 2);     // hn ping
    f16*   A1     = (f16*)carve((size_t)NN * HID * 2);     // hn pong
    f16*   C      = (f16*)carve((size_t)NN * HID * 2);     // hrb (own-row in place)
    unsigned* pairs = (unsigned*)carve((size_t)BKT * SLAB * 4);
    (void)ws_size;

    unsigned* Wn1_16 = w16;
    unsigned* Wr1_16 = w16 + 2048;
    unsigned* Wn2_16 = w16 + 4096;
    unsigned* Wr2_16 = w16 + 6144;
    unsigned* Wp1_16 = w16 + 8192;

    hipMemsetAsync(bfill, 0, (size_t)BKT * 4, stream);

    // merged: CSR placement || layer-0 transform (+ weight pack)
    mt_kernel<<<NWG + TB, 256, 0, stream>>>(src, dst, bfill, pairs,
                                            x, Wn0, bn0, Wr0, A0, C,
                                            Wn1, Wr1, Wn2, Wr2, Wp1, w16);
    // per-bucket counting sort
    build_kernel<<<BKT, 256, 0, stream>>>(pairs, bfill, rsA, reA, inv, col);

    // gather0 + transform1 (reads A0, writes A1 + C)
    gt_kernel<<<TB, 256, 0, stream>>>(A0, rsA, reA, col, inv, C, Wn1_16, bn1, Wr1_16, A1);
    // gather1 + transform2 (reads A1, writes A0 + C)
    gt_kernel<<<TB, 256, 0, stream>>>(A1, rsA, reA, col, inv, C, Wn2_16, bn2, Wr2_16, A0);
    // gather2 + head (reads A0 + C, writes out)
    gh_kernel<<<TB, 256, 0, stream>>>(A0, rsA, reA, col, inv, C, Wp1_16, bp1, Wp2, bp2, out);
}